// Round 1
// baseline (727.598 us; speedup 1.0000x reference)
//
#include <hip/hip_runtime.h>
#include <hip/hip_bf16.h>
#include <math.h>

#define B 8
#define C 256
#define HH 64
#define WW 64
#define NN 4096      // H*W
#define CI 128
#define NS 1024      // pooled spatial
#define EPS 1e-5f

// ---------------------------------------------------------------- K1: theta conv
// theta[b][n][ci] = sum_c tw[ci][c]*x[b][c][n] + tb[ci]
__global__ __launch_bounds__(256) void k_conv_theta(const float* __restrict__ x,
        const float* __restrict__ tw, const float* __restrict__ tb,
        float* __restrict__ theta) {
    int nb = blockIdx.x;          // 64 tiles of 64 n
    int cb = blockIdx.y;          // 4 tiles of 32 ci
    int b  = blockIdx.z;
    int lane = threadIdx.x & 63;
    int wv   = threadIdx.x >> 6;  // 0..3
    int n   = nb * 64 + lane;
    int ci0 = __builtin_amdgcn_readfirstlane(cb * 32 + wv * 8);  // wave-uniform -> SGPR
    float acc[8] = {0.f,0.f,0.f,0.f,0.f,0.f,0.f,0.f};
    const float* xp = x + (size_t)b * C * NN + n;
    for (int c = 0; c < C; ++c) {
        float xv = xp[(size_t)c * NN];
        #pragma unroll
        for (int j = 0; j < 8; ++j)
            acc[j] = fmaf(tw[(ci0 + j) * C + c], xv, acc[j]);
    }
    float* op = theta + ((size_t)b * NN + n) * CI + ci0;
    #pragma unroll
    for (int j = 0; j < 8; ++j) op[j] = acc[j] + tb[ci0 + j];
}

// ---------------------------------------------------------------- K2: pooled conv (phi / g)
// out = maxpool2(conv1x1(x,w,b)); layout: m_major=0 -> [b][ci][m] (phi), 1 -> [b][m][ci] (g)
__global__ __launch_bounds__(256) void k_conv_pool(const float* __restrict__ x,
        const float* __restrict__ w_, const float* __restrict__ b_,
        float* __restrict__ out, int out_m_major) {
    int mb = blockIdx.x;          // 16 tiles of 64 m
    int cb = blockIdx.y;          // 4 tiles of 32 ci
    int b  = blockIdx.z;
    int lane = threadIdx.x & 63;
    int wv   = threadIdx.x >> 6;
    int m  = mb * 64 + lane;      // 0..1023
    int mh = m >> 5, mw = m & 31;
    int ci0 = __builtin_amdgcn_readfirstlane(cb * 32 + wv * 8);
    int n00 = (mh * 2) * WW + mw * 2;
    float a0[8]={}, a1[8]={}, a2[8]={}, a3[8]={};
    const float* xp = x + (size_t)b * C * NN;
    for (int c = 0; c < C; ++c) {
        const float* xc = xp + (size_t)c * NN;
        float x0 = xc[n00], x1 = xc[n00 + 1], x2 = xc[n00 + WW], x3 = xc[n00 + WW + 1];
        #pragma unroll
        for (int j = 0; j < 8; ++j) {
            float wj = w_[(ci0 + j) * C + c];
            a0[j] = fmaf(wj, x0, a0[j]);
            a1[j] = fmaf(wj, x1, a1[j]);
            a2[j] = fmaf(wj, x2, a2[j]);
            a3[j] = fmaf(wj, x3, a3[j]);
        }
    }
    #pragma unroll
    for (int j = 0; j < 8; ++j) {
        float v = fmaxf(fmaxf(a0[j], a1[j]), fmaxf(a2[j], a3[j])) + b_[ci0 + j];
        if (out_m_major)
            out[((size_t)b * NS + m) * CI + ci0 + j] = v;       // g: [b][m][ci]
        else
            out[((size_t)b * CI + ci0 + j) * NS + m] = v;       // phi: [b][ci][m]
    }
}

// ---------------------------------------------------------------- K3: fused attention
// per block: 64 rows of theta, online softmax over 16 tiles of 64 m, y = softmax(theta*phi)*g
__global__ __launch_bounds__(512) void k_attn(const float* __restrict__ theta,
        const float* __restrict__ phi, const float* __restrict__ g,
        float* __restrict__ y) {
    __shared__ float s_th[64 * 128];   // theta rows      32 KB
    __shared__ float s_ph[128 * 64];   // phi tile        32 KB
    __shared__ float s_g[64 * 128];    // g tile          32 KB
    __shared__ float s_p[64 * 64];     // softmax probs   16 KB
    int rb = blockIdx.x;               // 64 row-blocks
    int b  = blockIdx.y;
    int tid = threadIdx.x;
    int lane16 = tid & 15;
    int grp = tid >> 4;                // 0..31, each owns 2 rows
    int r0  = grp * 2;
    int ci0 = lane16 * 8;
    int m0l = lane16 * 4;

    // stage theta rows (contiguous 64x128 block)
    {
        const float4* src = (const float4*)(theta + ((size_t)b * NN + rb * 64) * CI);
        float4* dst = (float4*)s_th;
        #pragma unroll
        for (int k = 0; k < 4; ++k) dst[tid + k * 512] = src[tid + k * 512];
    }

    float acc[2][8] = {};
    float mrun[2] = {-1e30f, -1e30f};
    float lrun[2] = {0.f, 0.f};

    for (int mt = 0; mt < 16; ++mt) {
        __syncthreads();   // protect s_ph/s_g/s_p from previous-iter readers
        {   // stage phi tile [128 ci][64 m]
            const float* pp = phi + (size_t)b * CI * NS + mt * 64;
            float4* d = (float4*)s_ph;
            #pragma unroll
            for (int k = 0; k < 4; ++k) {
                int idx = tid + k * 512;            // 2048 float4
                int row = idx >> 4, col = idx & 15;
                d[idx] = ((const float4*)(pp + (size_t)row * NS))[col];
            }
            // stage g tile [64 m][128 ci] (contiguous)
            const float4* gp = (const float4*)(g + ((size_t)b * NS + mt * 64) * CI);
            float4* dg = (float4*)s_g;
            #pragma unroll
            for (int k = 0; k < 4; ++k) dg[tid + k * 512] = gp[tid + k * 512];
        }
        __syncthreads();

        // logits: lg[2 rows][4 m]
        float lg[2][4] = {};
        for (int ci = 0; ci < 128; ++ci) {
            float t0 = s_th[r0 * 128 + ci];
            float t1 = s_th[(r0 + 1) * 128 + ci];
            float4 pv = *(const float4*)&s_ph[ci * 64 + m0l];
            lg[0][0] = fmaf(t0, pv.x, lg[0][0]);
            lg[0][1] = fmaf(t0, pv.y, lg[0][1]);
            lg[0][2] = fmaf(t0, pv.z, lg[0][2]);
            lg[0][3] = fmaf(t0, pv.w, lg[0][3]);
            lg[1][0] = fmaf(t1, pv.x, lg[1][0]);
            lg[1][1] = fmaf(t1, pv.y, lg[1][1]);
            lg[1][2] = fmaf(t1, pv.z, lg[1][2]);
            lg[1][3] = fmaf(t1, pv.w, lg[1][3]);
        }

        // online softmax update (16-lane groups share a row pair)
        #pragma unroll
        for (int i = 0; i < 2; ++i) {
            float tm = fmaxf(fmaxf(lg[i][0], lg[i][1]), fmaxf(lg[i][2], lg[i][3]));
            #pragma unroll
            for (int s = 1; s < 16; s <<= 1) tm = fmaxf(tm, __shfl_xor(tm, s));
            float mnew = fmaxf(mrun[i], tm);
            float scale = __expf(mrun[i] - mnew);
            float ps = 0.f;
            #pragma unroll
            for (int k2 = 0; k2 < 4; ++k2) {
                lg[i][k2] = __expf(lg[i][k2] - mnew);
                ps += lg[i][k2];
            }
            #pragma unroll
            for (int s = 1; s < 16; s <<= 1) ps += __shfl_xor(ps, s);
            lrun[i] = lrun[i] * scale + ps;
            mrun[i] = mnew;
            #pragma unroll
            for (int j = 0; j < 8; ++j) acc[i][j] *= scale;
            *(float4*)&s_p[(r0 + i) * 64 + m0l] = *(const float4*)&lg[i][0];
        }
        __syncthreads();

        // y accumulate: acc[r][j] += sum_m p[r][m] * g[m][ci0+j]
        for (int m = 0; m < 64; ++m) {
            float p0 = s_p[r0 * 64 + m];
            float p1 = s_p[(r0 + 1) * 64 + m];
            float4 g0 = *(const float4*)&s_g[m * 128 + ci0];
            float4 g1 = *(const float4*)&s_g[m * 128 + ci0 + 4];
            acc[0][0] = fmaf(p0, g0.x, acc[0][0]);
            acc[0][1] = fmaf(p0, g0.y, acc[0][1]);
            acc[0][2] = fmaf(p0, g0.z, acc[0][2]);
            acc[0][3] = fmaf(p0, g0.w, acc[0][3]);
            acc[0][4] = fmaf(p0, g1.x, acc[0][4]);
            acc[0][5] = fmaf(p0, g1.y, acc[0][5]);
            acc[0][6] = fmaf(p0, g1.z, acc[0][6]);
            acc[0][7] = fmaf(p0, g1.w, acc[0][7]);
            acc[1][0] = fmaf(p1, g0.x, acc[1][0]);
            acc[1][1] = fmaf(p1, g0.y, acc[1][1]);
            acc[1][2] = fmaf(p1, g0.z, acc[1][2]);
            acc[1][3] = fmaf(p1, g0.w, acc[1][3]);
            acc[1][4] = fmaf(p1, g1.x, acc[1][4]);
            acc[1][5] = fmaf(p1, g1.y, acc[1][5]);
            acc[1][6] = fmaf(p1, g1.z, acc[1][6]);
            acc[1][7] = fmaf(p1, g1.w, acc[1][7]);
        }
    }

    // normalize + write y[b][row][ci]
    #pragma unroll
    for (int i = 0; i < 2; ++i) {
        float inv = 1.f / lrun[i];
        float4 o0, o1;
        o0.x = acc[i][0] * inv; o0.y = acc[i][1] * inv;
        o0.z = acc[i][2] * inv; o0.w = acc[i][3] * inv;
        o1.x = acc[i][4] * inv; o1.y = acc[i][5] * inv;
        o1.z = acc[i][6] * inv; o1.w = acc[i][7] * inv;
        float* yp = y + ((size_t)b * NN + rb * 64 + r0 + i) * CI + ci0;
        *(float4*)yp = o0;
        *(float4*)(yp + 4) = o1;
    }
}

// ---------------------------------------------------------------- K4: W conv
// wy[b][co][n] = sum_ci ww[co][ci]*y[b][n][ci] + wb[co]
__global__ __launch_bounds__(256) void k_wconv(const float* __restrict__ y,
        const float* __restrict__ ww, const float* __restrict__ wb,
        float* __restrict__ wy) {
    __shared__ float s_y[64 * 129];
    int nb = blockIdx.x;   // 64
    int cb = blockIdx.y;   // 8 (32 co each)
    int b  = blockIdx.z;
    int tid = threadIdx.x;
    const float4* yp = (const float4*)(y + ((size_t)b * NN + nb * 64) * CI);
    #pragma unroll
    for (int k = 0; k < 8; ++k) {
        int idx = tid + k * 256;            // 2048 float4
        float4 v = yp[idx];
        int row = idx >> 5, col = (idx & 31) * 4;
        float* d = &s_y[row * 129 + col];
        d[0] = v.x; d[1] = v.y; d[2] = v.z; d[3] = v.w;
    }
    __syncthreads();
    int lane = tid & 63, wv = tid >> 6;
    int n   = nb * 64 + lane;
    int co0 = __builtin_amdgcn_readfirstlane(cb * 32 + wv * 8);
    float acc[8] = {};
    for (int ci = 0; ci < CI; ++ci) {
        float yv = s_y[lane * 129 + ci];
        #pragma unroll
        for (int j = 0; j < 8; ++j)
            acc[j] = fmaf(ww[(co0 + j) * CI + ci], yv, acc[j]);
    }
    #pragma unroll
    for (int j = 0; j < 8; ++j)
        wy[((size_t)b * C + co0 + j) * NN + n] = acc[j] + wb[co0 + j];
}

// ---------------------------------------------------------------- K4b: per-channel BN stats (deterministic)
__global__ __launch_bounds__(256) void k_stats(const float* __restrict__ wy,
                                               float* __restrict__ stats) {
    int c = blockIdx.x;
    int tid = threadIdx.x;
    float s = 0.f, sq = 0.f;
    for (int b = 0; b < B; ++b) {
        const float* p = wy + ((size_t)b * C + c) * NN;
        #pragma unroll 4
        for (int k = 0; k < 16; ++k) {
            float v = p[tid + k * 256];
            s += v;
            sq = fmaf(v, v, sq);
        }
    }
    #pragma unroll
    for (int o = 32; o >= 1; o >>= 1) {
        s  += __shfl_down(s, o);
        sq += __shfl_down(sq, o);
    }
    __shared__ float rs[4], rq[4];
    int lane = tid & 63, wv = tid >> 6;
    if (lane == 0) { rs[wv] = s; rq[wv] = sq; }
    __syncthreads();
    if (tid == 0) {
        stats[c]       = rs[0] + rs[1] + rs[2] + rs[3];
        stats[256 + c] = rq[0] + rq[1] + rq[2] + rq[3];
    }
}

// ---------------------------------------------------------------- K5: BN apply + residual
__global__ __launch_bounds__(256) void k_bn_out(const float* __restrict__ wy,
        const float* __restrict__ x, const float* __restrict__ stats,
        const float* __restrict__ gamma, const float* __restrict__ beta,
        float* __restrict__ out) {
    size_t idx = (size_t)blockIdx.x * 256 + threadIdx.x;  // float4 index
    int c = (int)(((idx * 4) >> 12) & 255);
    float mean = stats[c] * (1.f / 32768.f);
    float var  = stats[256 + c] * (1.f / 32768.f) - mean * mean;
    float sc = gamma[c] * rsqrtf(var + EPS);
    float sh = beta[c] - mean * sc;
    float4 w4 = ((const float4*)wy)[idx];
    float4 x4 = ((const float4*)x)[idx];
    float4 o;
    o.x = fmaf(w4.x, sc, sh) + x4.x;
    o.y = fmaf(w4.y, sc, sh) + x4.y;
    o.z = fmaf(w4.z, sc, sh) + x4.z;
    o.w = fmaf(w4.w, sc, sh) + x4.w;
    ((float4*)out)[idx] = o;
}

// ----------------------------------------------------------------
extern "C" void kernel_launch(void* const* d_in, const int* in_sizes, int n_in,
                              void* d_out, int out_size, void* d_ws, size_t ws_size,
                              hipStream_t stream) {
    const float* x    = (const float*)d_in[0];
    const float* g_w  = (const float*)d_in[1];
    const float* g_b  = (const float*)d_in[2];
    const float* th_w = (const float*)d_in[3];
    const float* th_b = (const float*)d_in[4];
    const float* ph_w = (const float*)d_in[5];
    const float* ph_b = (const float*)d_in[6];
    const float* w_w  = (const float*)d_in[7];
    const float* w_b  = (const float*)d_in[8];
    const float* bn_g = (const float*)d_in[9];
    const float* bn_b = (const float*)d_in[10];
    float* out = (float*)d_out;

    float* ws    = (float*)d_ws;
    float* theta = ws;                  // [B][N][CI]   4,194,304 f
    float* phi   = ws + 4194304;        // [B][CI][NS]  1,048,576 f
    float* gx    = ws + 5242880;        // [B][NS][CI]  1,048,576 f
    float* y     = ws + 6291456;        // [B][N][CI]   4,194,304 f
    float* wy    = ws + 10485760;       // [B][C][N]    8,388,608 f
    float* stats = ws + 18874368;       // 512 f

    k_conv_theta<<<dim3(64, 4, B), 256, 0, stream>>>(x, th_w, th_b, theta);
    k_conv_pool<<<dim3(16, 4, B), 256, 0, stream>>>(x, ph_w, ph_b, phi, 0);
    k_conv_pool<<<dim3(16, 4, B), 256, 0, stream>>>(x, g_w, g_b, gx, 1);
    k_attn<<<dim3(64, B), 512, 0, stream>>>(theta, phi, gx, y);
    k_wconv<<<dim3(64, 8, B), 256, 0, stream>>>(y, w_w, w_b, wy);
    k_stats<<<256, 256, 0, stream>>>(wy, stats);
    k_bn_out<<<8192, 256, 0, stream>>>(wy, x, stats, bn_g, bn_b, out);
}

// Round 3
// 399.430 us; speedup vs baseline: 1.8216x; 1.8216x over previous
//
#include <hip/hip_runtime.h>
#include <hip/hip_bf16.h>
#include <hip/hip_fp16.h>
#include <math.h>

#define B 8
#define C 256
#define HH 64
#define WW 64
#define NN 4096      // H*W
#define CI 128
#define NS 1024      // pooled spatial
#define EPS 1e-5f

typedef __attribute__((ext_vector_type(8))) _Float16 f16x8;
typedef __attribute__((ext_vector_type(4))) float f32x4;

static __device__ __forceinline__ unsigned short f2h_bits(float f) {
    return __half_as_ushort(__float2half(f));   // v_cvt_f16_f32 (RNE)
}

// ---------------------------------------------------------------- K1: theta conv -> fp16 [b][n][ci]
__global__ __launch_bounds__(256) void k_conv_theta(const float* __restrict__ x,
        const float* __restrict__ tw, const float* __restrict__ tb,
        unsigned short* __restrict__ theta) {
    int nb = blockIdx.x;          // 64 tiles of 64 n
    int cb = blockIdx.y;          // 4 tiles of 32 ci
    int b  = blockIdx.z;
    int lane = threadIdx.x & 63;
    int wv   = threadIdx.x >> 6;  // 0..3
    int n   = nb * 64 + lane;
    int ci0 = __builtin_amdgcn_readfirstlane(cb * 32 + wv * 8);  // wave-uniform -> SGPR
    float acc[8] = {};
    const float* xp = x + (size_t)b * C * NN + n;
    for (int c = 0; c < C; ++c) {
        float xv = xp[(size_t)c * NN];
        #pragma unroll
        for (int j = 0; j < 8; ++j)
            acc[j] = fmaf(tw[(ci0 + j) * C + c], xv, acc[j]);
    }
    ushort4 o0, o1;
    o0.x = f2h_bits(acc[0] + tb[ci0 + 0]);
    o0.y = f2h_bits(acc[1] + tb[ci0 + 1]);
    o0.z = f2h_bits(acc[2] + tb[ci0 + 2]);
    o0.w = f2h_bits(acc[3] + tb[ci0 + 3]);
    o1.x = f2h_bits(acc[4] + tb[ci0 + 4]);
    o1.y = f2h_bits(acc[5] + tb[ci0 + 5]);
    o1.z = f2h_bits(acc[6] + tb[ci0 + 6]);
    o1.w = f2h_bits(acc[7] + tb[ci0 + 7]);
    unsigned short* op = theta + ((size_t)b * NN + n) * CI + ci0;
    *(ushort4*)op = o0;
    *(ushort4*)(op + 4) = o1;
}

// ---------------------------------------------------------------- K2: pooled conv (phi / g) -> fp16
// out = maxpool2(conv1x1(x,w,b)); m_major=1 -> [b][m][ci] (phi), 0 -> [b][ci][m] (g)
__global__ __launch_bounds__(256) void k_conv_pool(const float* __restrict__ x,
        const float* __restrict__ w_, const float* __restrict__ b_,
        unsigned short* __restrict__ out, int out_m_major) {
    int mb = blockIdx.x;          // 16 tiles of 64 m
    int cb = blockIdx.y;          // 4 tiles of 32 ci
    int b  = blockIdx.z;
    int lane = threadIdx.x & 63;
    int wv   = threadIdx.x >> 6;
    int m  = mb * 64 + lane;      // 0..1023
    int mh = m >> 5, mw = m & 31;
    int ci0 = __builtin_amdgcn_readfirstlane(cb * 32 + wv * 8);
    int n00 = (mh * 2) * WW + mw * 2;
    float a0[8]={}, a1[8]={}, a2[8]={}, a3[8]={};
    const float* xp = x + (size_t)b * C * NN;
    for (int c = 0; c < C; ++c) {
        const float* xc = xp + (size_t)c * NN;
        float x0 = xc[n00], x1 = xc[n00 + 1], x2 = xc[n00 + WW], x3 = xc[n00 + WW + 1];
        #pragma unroll
        for (int j = 0; j < 8; ++j) {
            float wj = w_[(ci0 + j) * C + c];
            a0[j] = fmaf(wj, x0, a0[j]);
            a1[j] = fmaf(wj, x1, a1[j]);
            a2[j] = fmaf(wj, x2, a2[j]);
            a3[j] = fmaf(wj, x3, a3[j]);
        }
    }
    float v[8];
    #pragma unroll
    for (int j = 0; j < 8; ++j)
        v[j] = fmaxf(fmaxf(a0[j], a1[j]), fmaxf(a2[j], a3[j])) + b_[ci0 + j];
    if (out_m_major) {
        ushort4 o0, o1;
        o0.x = f2h_bits(v[0]); o0.y = f2h_bits(v[1]);
        o0.z = f2h_bits(v[2]); o0.w = f2h_bits(v[3]);
        o1.x = f2h_bits(v[4]); o1.y = f2h_bits(v[5]);
        o1.z = f2h_bits(v[6]); o1.w = f2h_bits(v[7]);
        unsigned short* op = out + ((size_t)b * NS + m) * CI + ci0;
        *(ushort4*)op = o0;
        *(ushort4*)(op + 4) = o1;
    } else {
        #pragma unroll
        for (int j = 0; j < 8; ++j)
            out[((size_t)b * CI + ci0 + j) * NS + m] = f2h_bits(v[j]);
    }
}

// ---------------------------------------------------------------- K3: fused attention (fp16 MFMA, flash-style)
// theta [b][n][ci] f16, phi [b][m][ci] f16, g [b][ci][m] f16 -> y [b][n][ci] f32
#define SPH 136   // 128+8 f16, row stride (272B = 4 banks mod 32)
#define SG  72    // 64+8 f16  (144B = 4 banks mod 32)
#define SP  72
__global__ __launch_bounds__(256) void k_attn_mfma(const unsigned short* __restrict__ theta,
        const unsigned short* __restrict__ phi, const unsigned short* __restrict__ g,
        float* __restrict__ y) {
    __shared__ unsigned short s_ph[64 * SPH];   // phi tile [m_local][ci]   17408 B
    __shared__ unsigned short s_g[128 * SG];    // g tile  [ci][m_local]    18432 B
    __shared__ unsigned short s_p[64 * SP];     // P       [row_local][m_local] 9216 B
    int rb = blockIdx.x;               // 64 row-blocks of 64
    int b  = blockIdx.y;
    int tid = threadIdx.x;
    int lane = tid & 63, wv = tid >> 6;
    int lr = lane & 15;                // fragment row/col index
    int lh = lane >> 4;                // 0..3 (k-group)
    int row0 = rb * 64;
    int wrow = wv * 16;                // wave's local row base

    // theta A-fragments, loaded once, reused for all 16 m-tiles
    f16x8 a_th[4];
    {
        const unsigned short* tp = theta + ((size_t)b * NN + row0 + wrow + lr) * CI + lh * 8;
        #pragma unroll
        for (int kc = 0; kc < 4; ++kc)
            a_th[kc] = *(const f16x8*)(tp + kc * 32);
    }

    f32x4 yacc[8];
    #pragma unroll
    for (int i = 0; i < 8; ++i) yacc[i] = (f32x4){0.f, 0.f, 0.f, 0.f};
    float mrun[4] = {-1e30f, -1e30f, -1e30f, -1e30f};
    float lrun[4] = {0.f, 0.f, 0.f, 0.f};

    for (int mt = 0; mt < 16; ++mt) {
        __syncthreads();   // protect s_ph/s_g from previous-iter readers
        // stage phi tile: rows m_local 0..63, 128 f16 each (32 ushort4/row)
        {
            const ushort4* src = (const ushort4*)(phi + ((size_t)b * NS + mt * 64) * CI);
            #pragma unroll
            for (int k = 0; k < 8; ++k) {
                int t = tid + k * 256;        // 0..2047
                int r = t >> 5, cq = t & 31;
                ushort4 vv = src[r * 32 + cq];
                *(ushort4*)&s_ph[r * SPH + cq * 4] = vv;
            }
            // stage g tile: 128 ci-rows x 64 m (16 ushort4/row)
            const ushort4* sg = (const ushort4*)(g + (size_t)b * CI * NS);
            #pragma unroll
            for (int k = 0; k < 8; ++k) {
                int t = tid + k * 256;
                int ci = t >> 4, cq = t & 15;
                ushort4 vv = sg[ci * 256 + mt * 16 + cq];
                *(ushort4*)&s_g[ci * SG + cq * 4] = vv;
            }
        }
        __syncthreads();

        // ---- S = theta * phi^T : 4 n-tiles of 16 cols
        f32x4 S[4];
        #pragma unroll
        for (int nt = 0; nt < 4; ++nt) S[nt] = (f32x4){0.f, 0.f, 0.f, 0.f};
        #pragma unroll
        for (int nt = 0; nt < 4; ++nt) {
            #pragma unroll
            for (int kc = 0; kc < 4; ++kc) {
                f16x8 bf = *(const f16x8*)&s_ph[(nt * 16 + lr) * SPH + kc * 32 + lh * 8];
                S[nt] = __builtin_amdgcn_mfma_f32_16x16x32_f16(a_th[kc], bf, S[nt], 0, 0, 0);
            }
        }

        // ---- online softmax; lane owns rows (lh*4 + r), r=0..3; cols spread over lr (lane bits 0-3)
        float rmax[4], rs[4], scale[4];
        #pragma unroll
        for (int r = 0; r < 4; ++r)
            rmax[r] = fmaxf(fmaxf(S[0][r], S[1][r]), fmaxf(S[2][r], S[3][r]));
        #pragma unroll
        for (int s = 1; s < 16; s <<= 1) {
            #pragma unroll
            for (int r = 0; r < 4; ++r) rmax[r] = fmaxf(rmax[r], __shfl_xor(rmax[r], s));
        }
        #pragma unroll
        for (int r = 0; r < 4; ++r) {
            float mnew = fmaxf(mrun[r], rmax[r]);
            scale[r] = __expf(mrun[r] - mnew);
            mrun[r] = mnew;
            rs[r] = 0.f;
        }
        #pragma unroll
        for (int nt = 0; nt < 4; ++nt) {
            #pragma unroll
            for (int r = 0; r < 4; ++r) {
                float e = __expf(S[nt][r] - mrun[r]);
                S[nt][r] = e;
                rs[r] += e;
            }
        }
        #pragma unroll
        for (int s = 1; s < 16; s <<= 1) {
            #pragma unroll
            for (int r = 0; r < 4; ++r) rs[r] += __shfl_xor(rs[r], s);
        }
        #pragma unroll
        for (int r = 0; r < 4; ++r) lrun[r] = lrun[r] * scale[r] + rs[r];
        #pragma unroll
        for (int i = 0; i < 8; ++i) {
            #pragma unroll
            for (int r = 0; r < 4; ++r) yacc[i][r] *= scale[r];
        }
        // write P (f16) to wave-private rows of s_p; same wave reads it back -> no barrier
        #pragma unroll
        for (int nt = 0; nt < 4; ++nt) {
            #pragma unroll
            for (int r = 0; r < 4; ++r)
                s_p[(wrow + lh * 4 + r) * SP + nt * 16 + lr] = f2h_bits(S[nt][r]);
        }

        // ---- y += P * g : 8 ci-tiles, K=64 in 2 chunks
        f16x8 a_p[2];
        #pragma unroll
        for (int kc = 0; kc < 2; ++kc)
            a_p[kc] = *(const f16x8*)&s_p[(wrow + lr) * SP + kc * 32 + lh * 8];
        #pragma unroll
        for (int ct = 0; ct < 8; ++ct) {
            #pragma unroll
            for (int kc = 0; kc < 2; ++kc) {
                f16x8 bg = *(const f16x8*)&s_g[(ct * 16 + lr) * SG + kc * 32 + lh * 8];
                yacc[ct] = __builtin_amdgcn_mfma_f32_16x16x32_f16(a_p[kc], bg, yacc[ct], 0, 0, 0);
            }
        }
    }

    // normalize + write y[b][row][ci] f32
    float inv[4];
    #pragma unroll
    for (int r = 0; r < 4; ++r) inv[r] = 1.f / lrun[r];
    #pragma unroll
    for (int ct = 0; ct < 8; ++ct) {
        #pragma unroll
        for (int r = 0; r < 4; ++r) {
            y[((size_t)b * NN + row0 + wrow + lh * 4 + r) * CI + ct * 16 + lr] = yacc[ct][r] * inv[r];
        }
    }
}

// ---------------------------------------------------------------- K4: W conv
// wy[b][co][n] = sum_ci ww[co][ci]*y[b][n][ci] + wb[co]
__global__ __launch_bounds__(256) void k_wconv(const float* __restrict__ y,
        const float* __restrict__ ww, const float* __restrict__ wb,
        float* __restrict__ wy) {
    __shared__ float s_y[64 * 129];
    int nb = blockIdx.x;   // 64
    int cb = blockIdx.y;   // 8 (32 co each)
    int b  = blockIdx.z;
    int tid = threadIdx.x;
    const float4* yp = (const float4*)(y + ((size_t)b * NN + nb * 64) * CI);
    #pragma unroll
    for (int k = 0; k < 8; ++k) {
        int idx = tid + k * 256;            // 2048 float4
        float4 v = yp[idx];
        int row = idx >> 5, col = (idx & 31) * 4;
        float* d = &s_y[row * 129 + col];
        d[0] = v.x; d[1] = v.y; d[2] = v.z; d[3] = v.w;
    }
    __syncthreads();
    int lane = tid & 63, wv = tid >> 6;
    int n   = nb * 64 + lane;
    int co0 = __builtin_amdgcn_readfirstlane(cb * 32 + wv * 8);
    float acc[8] = {};
    for (int ci = 0; ci < CI; ++ci) {
        float yv = s_y[lane * 129 + ci];
        #pragma unroll
        for (int j = 0; j < 8; ++j)
            acc[j] = fmaf(ww[(co0 + j) * CI + ci], yv, acc[j]);
    }
    #pragma unroll
    for (int j = 0; j < 8; ++j)
        wy[((size_t)b * C + co0 + j) * NN + n] = acc[j] + wb[co0 + j];
}

// ---------------------------------------------------------------- K4b: per-channel BN stats (deterministic)
__global__ __launch_bounds__(256) void k_stats(const float* __restrict__ wy,
                                               float* __restrict__ stats) {
    int c = blockIdx.x;
    int tid = threadIdx.x;
    float s = 0.f, sq = 0.f;
    for (int b = 0; b < B; ++b) {
        const float* p = wy + ((size_t)b * C + c) * NN;
        #pragma unroll 4
        for (int k = 0; k < 16; ++k) {
            float v = p[tid + k * 256];
            s += v;
            sq = fmaf(v, v, sq);
        }
    }
    #pragma unroll
    for (int o = 32; o >= 1; o >>= 1) {
        s  += __shfl_down(s, o);
        sq += __shfl_down(sq, o);
    }
    __shared__ float rs[4], rq[4];
    int lane = tid & 63, wv = tid >> 6;
    if (lane == 0) { rs[wv] = s; rq[wv] = sq; }
    __syncthreads();
    if (tid == 0) {
        stats[c]       = rs[0] + rs[1] + rs[2] + rs[3];
        stats[256 + c] = rq[0] + rq[1] + rq[2] + rq[3];
    }
}

// ---------------------------------------------------------------- K5: BN apply + residual
__global__ __launch_bounds__(256) void k_bn_out(const float* __restrict__ wy,
        const float* __restrict__ x, const float* __restrict__ stats,
        const float* __restrict__ gamma, const float* __restrict__ beta,
        float* __restrict__ out) {
    size_t idx = (size_t)blockIdx.x * 256 + threadIdx.x;  // float4 index
    int c = (int)(((idx * 4) >> 12) & 255);
    float mean = stats[c] * (1.f / 32768.f);
    float var  = stats[256 + c] * (1.f / 32768.f) - mean * mean;
    float sc = gamma[c] * rsqrtf(var + EPS);
    float sh = beta[c] - mean * sc;
    float4 w4 = ((const float4*)wy)[idx];
    float4 x4 = ((const float4*)x)[idx];
    float4 o;
    o.x = fmaf(w4.x, sc, sh) + x4.x;
    o.y = fmaf(w4.y, sc, sh) + x4.y;
    o.z = fmaf(w4.z, sc, sh) + x4.z;
    o.w = fmaf(w4.w, sc, sh) + x4.w;
    ((float4*)out)[idx] = o;
}

// ----------------------------------------------------------------
extern "C" void kernel_launch(void* const* d_in, const int* in_sizes, int n_in,
                              void* d_out, int out_size, void* d_ws, size_t ws_size,
                              hipStream_t stream) {
    const float* x    = (const float*)d_in[0];
    const float* g_w  = (const float*)d_in[1];
    const float* g_b  = (const float*)d_in[2];
    const float* th_w = (const float*)d_in[3];
    const float* th_b = (const float*)d_in[4];
    const float* ph_w = (const float*)d_in[5];
    const float* ph_b = (const float*)d_in[6];
    const float* w_w  = (const float*)d_in[7];
    const float* w_b  = (const float*)d_in[8];
    const float* bn_g = (const float*)d_in[9];
    const float* bn_b = (const float*)d_in[10];
    float* out = (float*)d_out;

    char* w0 = (char*)d_ws;
    unsigned short* theta = (unsigned short*)w0;                 // [B][N][CI] f16  8,388,608 B
    unsigned short* phi   = (unsigned short*)(w0 + 8388608);     // [B][m][CI] f16  2,097,152 B
    unsigned short* gx    = (unsigned short*)(w0 + 10485760);    // [B][CI][m] f16  2,097,152 B
    float*  y     = (float*)(w0 + 12582912);                     // [B][N][CI] f32  16,777,216 B
    float*  wy    = (float*)(w0 + 29360128);                     // [B][C][N]  f32  33,554,432 B
    float*  stats = (float*)(w0 + 62914560);                     // 512 f32

    k_conv_theta<<<dim3(64, 4, B), 256, 0, stream>>>(x, th_w, th_b, theta);
    k_conv_pool<<<dim3(16, 4, B), 256, 0, stream>>>(x, ph_w, ph_b, phi, 1);  // phi: [b][m][ci]
    k_conv_pool<<<dim3(16, 4, B), 256, 0, stream>>>(x, g_w, g_b, gx, 0);     // g:   [b][ci][m]
    k_attn_mfma<<<dim3(64, B), 256, 0, stream>>>(theta, phi, gx, y);
    k_wconv<<<dim3(64, 8, B), 256, 0, stream>>>(y, w_w, w_b, wy);
    k_stats<<<256, 256, 0, stream>>>(wy, stats);
    k_bn_out<<<8192, 256, 0, stream>>>(wy, x, stats, bn_g, bn_b, out);
}

// Round 4
// 226.130 us; speedup vs baseline: 3.2176x; 1.7664x over previous
//
#include <hip/hip_runtime.h>
#include <hip/hip_bf16.h>
#include <hip/hip_fp16.h>
#include <math.h>

#define B 8
#define C 256
#define HH 64
#define WW 64
#define NN 4096      // H*W
#define CI 128
#define NS 1024      // pooled spatial
#define EPS 1e-5f

typedef __attribute__((ext_vector_type(8))) _Float16 f16x8;
typedef __attribute__((ext_vector_type(4))) float f32x4;

static __device__ __forceinline__ unsigned short f2h_bits(float f) {
    return __half_as_ushort(__float2half(f));   // v_cvt_f16_f32 (RNE)
}

// ---------------------------------------------------------------- K0: weights -> f16
// tw, pw, gw are [128][256]=32768; ww is [256][128]=32768. 4 arrays x 32768.
__global__ __launch_bounds__(256) void k_prep(const float* __restrict__ tw,
        const float* __restrict__ pw, const float* __restrict__ gw,
        const float* __restrict__ ww, unsigned short* __restrict__ wh) {
    int idx = blockIdx.x * 256 + threadIdx.x;          // 0..131071
    int sel = idx >> 15, off = idx & 32767;
    const float* src = (sel == 0) ? tw : (sel == 1) ? pw : (sel == 2) ? gw : ww;
    wh[idx] = f2h_bits(src[off]);
}

// ---------------------------------------------------------------- K0b: x [b][c][n] f32 -> xh [b][n][c] f16
__global__ __launch_bounds__(256) void k_xt(const float* __restrict__ x,
                                            unsigned short* __restrict__ xh) {
    __shared__ float s_t[64 * 65];
    int n0 = blockIdx.x * 64;
    int c0 = blockIdx.y * 64;
    int b  = blockIdx.z;
    int tid = threadIdx.x;
    #pragma unroll
    for (int k = 0; k < 16; ++k) {
        int idx = tid + k * 256;           // 0..4095
        int cl = idx >> 6, nl = idx & 63;
        s_t[cl * 65 + nl] = x[((size_t)b * C + c0 + cl) * NN + n0 + nl];
    }
    __syncthreads();
    #pragma unroll
    for (int k = 0; k < 8; ++k) {
        int idx = tid + k * 256;           // 0..2047
        int nl = idx >> 5, cp = (idx & 31) * 2;
        ushort2 o;
        o.x = f2h_bits(s_t[cp * 65 + nl]);
        o.y = f2h_bits(s_t[(cp + 1) * 65 + nl]);
        *(ushort2*)&xh[((size_t)b * NN + n0 + nl) * C + c0 + cp] = o;
    }
}

// ---------------------------------------------------------------- K1: theta conv (MFMA)
// theta[gr][ci] = sum_c xh[gr][c]*twh[ci][c] + tb[ci];  gr = global row (b*NN+n)
__global__ __launch_bounds__(256) void k_conv_theta(const unsigned short* __restrict__ xh,
        const unsigned short* __restrict__ twh, const float* __restrict__ tb,
        unsigned short* __restrict__ theta) {
    int blk = blockIdx.x;                 // 512 blocks of 64 rows
    int tid = threadIdx.x;
    int lane = tid & 63, wv = tid >> 6;
    int lr = lane & 15, lh = lane >> 4;
    int rowf = blk * 64 + wv * 16 + lr;   // A-frag row

    f32x4 acc[8];
    #pragma unroll
    for (int i = 0; i < 8; ++i) acc[i] = (f32x4){0.f, 0.f, 0.f, 0.f};

    const unsigned short* ap = xh + (size_t)rowf * C + lh * 8;
    #pragma unroll
    for (int kc = 0; kc < 8; ++kc) {
        f16x8 a = *(const f16x8*)(ap + kc * 32);
        #pragma unroll
        for (int ct = 0; ct < 8; ++ct) {
            f16x8 bf = *(const f16x8*)&twh[(ct * 16 + lr) * C + kc * 32 + lh * 8];
            acc[ct] = __builtin_amdgcn_mfma_f32_16x16x32_f16(a, bf, acc[ct], 0, 0, 0);
        }
    }
    int rowo = blk * 64 + wv * 16 + lh * 4;
    #pragma unroll
    for (int ct = 0; ct < 8; ++ct) {
        int ci = ct * 16 + lr;
        float bias = tb[ci];
        #pragma unroll
        for (int r = 0; r < 4; ++r)
            theta[(size_t)(rowo + r) * CI + ci] = f2h_bits(acc[ct][r] + bias);
    }
}

// ---------------------------------------------------------------- K2: pooled conv (MFMA, in-register 2x2 maxpool)
// block: 128 n-rows (= 2 h-rows), 512 thr / 8 waves; wave (wn=wv&3, wc=wv>>2)
// m_major=1 -> phi [b][m][ci]; 0 -> g [b][ci][m]
__global__ __launch_bounds__(512) void k_conv_pool(const unsigned short* __restrict__ xh,
        const unsigned short* __restrict__ wh, const float* __restrict__ b_,
        unsigned short* __restrict__ out, int out_m_major) {
    int blk = blockIdx.x;                 // 256 blocks
    int b   = blk >> 5;                   // 32 blocks per batch
    int mh  = blk & 31;                   // pooled h row
    int tid = threadIdx.x;
    int lane = tid & 63, wv = tid >> 6;
    int lr = lane & 15, lh = lane >> 4;
    int wn = wv & 3, wc = wv >> 2;
    size_t row0 = (size_t)blk * 128;

    f32x4 acc0[4], acc1[4];
    #pragma unroll
    for (int i = 0; i < 4; ++i) { acc0[i] = (f32x4){0,0,0,0}; acc1[i] = (f32x4){0,0,0,0}; }

    const unsigned short* ap0 = xh + (row0 + wn * 16 + lr) * C + lh * 8;
    const unsigned short* ap1 = ap0 + (size_t)64 * C;
    #pragma unroll
    for (int kc = 0; kc < 8; ++kc) {
        f16x8 a0 = *(const f16x8*)(ap0 + kc * 32);
        f16x8 a1 = *(const f16x8*)(ap1 + kc * 32);
        #pragma unroll
        for (int ct = 0; ct < 4; ++ct) {
            f16x8 bf = *(const f16x8*)&wh[(wc * 64 + ct * 16 + lr) * C + kc * 32 + lh * 8];
            acc0[ct] = __builtin_amdgcn_mfma_f32_16x16x32_f16(a0, bf, acc0[ct], 0, 0, 0);
            acc1[ct] = __builtin_amdgcn_mfma_f32_16x16x32_f16(a1, bf, acc1[ct], 0, 0, 0);
        }
    }
    // pool: w-adjacent = reg pairs (2j,2j+1); h-adjacent = acc0 vs acc1
    #pragma unroll
    for (int ct = 0; ct < 4; ++ct) {
        int ci = wc * 64 + ct * 16 + lr;
        float bias = b_[ci];
        #pragma unroll
        for (int j = 0; j < 2; ++j) {
            float v = fmaxf(fmaxf(acc0[ct][2*j], acc0[ct][2*j+1]),
                            fmaxf(acc1[ct][2*j], acc1[ct][2*j+1])) + bias;
            int m = mh * 32 + wn * 8 + lh * 2 + j;
            if (out_m_major)
                out[((size_t)b * NS + m) * CI + ci] = f2h_bits(v);
            else
                out[((size_t)b * CI + ci) * NS + m] = f2h_bits(v);
        }
    }
}

// ---------------------------------------------------------------- K3: fused attention (fp16 MFMA, no barriers)
// theta [b][n][ci] f16, phi [b][m][ci] f16, g [b][ci][m] f16 -> y [b][n][ci] f16
#define SP 72
__global__ __launch_bounds__(256) void k_attn_mfma(const unsigned short* __restrict__ theta,
        const unsigned short* __restrict__ phi, const unsigned short* __restrict__ g,
        unsigned short* __restrict__ y) {
    __shared__ unsigned short s_p[64 * SP];   // P [row_local][m_local], wave-private rows
    int rb = blockIdx.x;               // 64 row-blocks of 64
    int b  = blockIdx.y;
    int tid = threadIdx.x;
    int lane = tid & 63, wv = tid >> 6;
    int lr = lane & 15, lh = lane >> 4;
    int row0 = rb * 64;
    int wrow = wv * 16;

    f16x8 a_th[4];
    {
        const unsigned short* tp = theta + ((size_t)b * NN + row0 + wrow + lr) * CI + lh * 8;
        #pragma unroll
        for (int kc = 0; kc < 4; ++kc) a_th[kc] = *(const f16x8*)(tp + kc * 32);
    }

    f32x4 yacc[8];
    #pragma unroll
    for (int i = 0; i < 8; ++i) yacc[i] = (f32x4){0.f, 0.f, 0.f, 0.f};
    float mrun[4] = {-1e30f, -1e30f, -1e30f, -1e30f};
    float lrun[4] = {0.f, 0.f, 0.f, 0.f};

    const unsigned short* phb = phi + (size_t)b * NS * CI;
    const unsigned short* gb  = g + (size_t)b * CI * NS;

    for (int mt = 0; mt < 16; ++mt) {
        // ---- S = theta * phi^T
        f32x4 S[4];
        #pragma unroll
        for (int nt = 0; nt < 4; ++nt) S[nt] = (f32x4){0.f, 0.f, 0.f, 0.f};
        #pragma unroll
        for (int nt = 0; nt < 4; ++nt) {
            const unsigned short* pp = phb + (size_t)(mt * 64 + nt * 16 + lr) * CI + lh * 8;
            #pragma unroll
            for (int kc = 0; kc < 4; ++kc) {
                f16x8 bf = *(const f16x8*)(pp + kc * 32);
                S[nt] = __builtin_amdgcn_mfma_f32_16x16x32_f16(a_th[kc], bf, S[nt], 0, 0, 0);
            }
        }

        // ---- online softmax (rows lh*4+r; 16-lane col groups)
        float rmax[4], rs[4], scale[4];
        #pragma unroll
        for (int r = 0; r < 4; ++r)
            rmax[r] = fmaxf(fmaxf(S[0][r], S[1][r]), fmaxf(S[2][r], S[3][r]));
        #pragma unroll
        for (int s = 1; s < 16; s <<= 1) {
            #pragma unroll
            for (int r = 0; r < 4; ++r) rmax[r] = fmaxf(rmax[r], __shfl_xor(rmax[r], s));
        }
        #pragma unroll
        for (int r = 0; r < 4; ++r) {
            float mnew = fmaxf(mrun[r], rmax[r]);
            scale[r] = __expf(mrun[r] - mnew);
            mrun[r] = mnew;
            rs[r] = 0.f;
        }
        #pragma unroll
        for (int nt = 0; nt < 4; ++nt) {
            #pragma unroll
            for (int r = 0; r < 4; ++r) {
                float e = __expf(S[nt][r] - mrun[r]);
                S[nt][r] = e;
                rs[r] += e;
            }
        }
        #pragma unroll
        for (int s = 1; s < 16; s <<= 1) {
            #pragma unroll
            for (int r = 0; r < 4; ++r) rs[r] += __shfl_xor(rs[r], s);
        }
        #pragma unroll
        for (int r = 0; r < 4; ++r) lrun[r] = lrun[r] * scale[r] + rs[r];
        #pragma unroll
        for (int i = 0; i < 8; ++i) {
            #pragma unroll
            for (int r = 0; r < 4; ++r) yacc[i][r] *= scale[r];
        }
        // P -> wave-private LDS rows (same wave reads back; no barrier)
        #pragma unroll
        for (int nt = 0; nt < 4; ++nt) {
            #pragma unroll
            for (int r = 0; r < 4; ++r)
                s_p[(wrow + lh * 4 + r) * SP + nt * 16 + lr] = f2h_bits(S[nt][r]);
        }

        // ---- y += P * g
        f16x8 a_p[2];
        #pragma unroll
        for (int kc = 0; kc < 2; ++kc)
            a_p[kc] = *(const f16x8*)&s_p[(wrow + lr) * SP + kc * 32 + lh * 8];
        #pragma unroll
        for (int ct = 0; ct < 8; ++ct) {
            const unsigned short* gp = gb + (size_t)(ct * 16 + lr) * NS + mt * 64 + lh * 8;
            #pragma unroll
            for (int kc = 0; kc < 2; ++kc) {
                f16x8 bg = *(const f16x8*)(gp + kc * 32);
                yacc[ct] = __builtin_amdgcn_mfma_f32_16x16x32_f16(a_p[kc], bg, yacc[ct], 0, 0, 0);
            }
        }
    }

    float inv[4];
    #pragma unroll
    for (int r = 0; r < 4; ++r) inv[r] = 1.f / lrun[r];
    #pragma unroll
    for (int ct = 0; ct < 8; ++ct) {
        #pragma unroll
        for (int r = 0; r < 4; ++r)
            y[((size_t)b * NN + row0 + wrow + lh * 4 + r) * CI + ct * 16 + lr] =
                f2h_bits(yacc[ct][r] * inv[r]);
    }
}

// ---------------------------------------------------------------- K4: W conv (MFMA)
// wy[b][co][n] = sum_ci wwh[co][ci]*y[b][n][ci] + wb[co]
__global__ __launch_bounds__(256) void k_wconv(const unsigned short* __restrict__ y,
        const unsigned short* __restrict__ wwh, const float* __restrict__ wb,
        float* __restrict__ wy) {
    int blk = blockIdx.x;                  // 512 blocks of 64 n
    int b   = blk >> 6;
    int nloc = (blk & 63) * 64;
    int tid = threadIdx.x;
    int lane = tid & 63, wv = tid >> 6;
    int lr = lane & 15, lh = lane >> 4;

    f32x4 acc[4][4];
    #pragma unroll
    for (int i = 0; i < 4; ++i)
        #pragma unroll
        for (int j = 0; j < 4; ++j) acc[i][j] = (f32x4){0.f, 0.f, 0.f, 0.f};

    const unsigned short* yb = y + ((size_t)b * NN + nloc) * CI;
    #pragma unroll
    for (int kc = 0; kc < 4; ++kc) {
        f16x8 a[4], bf[4];
        #pragma unroll
        for (int at = 0; at < 4; ++at)
            a[at] = *(const f16x8*)&wwh[(wv * 64 + at * 16 + lr) * CI + kc * 32 + lh * 8];
        #pragma unroll
        for (int bt = 0; bt < 4; ++bt)
            bf[bt] = *(const f16x8*)&yb[(size_t)(bt * 16 + lr) * CI + kc * 32 + lh * 8];
        #pragma unroll
        for (int at = 0; at < 4; ++at)
            #pragma unroll
            for (int bt = 0; bt < 4; ++bt)
                acc[at][bt] = __builtin_amdgcn_mfma_f32_16x16x32_f16(a[at], bf[bt], acc[at][bt], 0, 0, 0);
    }
    #pragma unroll
    for (int at = 0; at < 4; ++at) {
        #pragma unroll
        for (int r = 0; r < 4; ++r) {
            int co = wv * 64 + at * 16 + lh * 4 + r;
            float bias = wb[co];
            float* wp = wy + ((size_t)b * C + co) * NN + nloc;
            #pragma unroll
            for (int bt = 0; bt < 4; ++bt)
                wp[bt * 16 + lr] = acc[at][bt][r] + bias;
        }
    }
}

// ---------------------------------------------------------------- K4b: per-channel BN stats (deterministic)
__global__ __launch_bounds__(256) void k_stats(const float* __restrict__ wy,
                                               float* __restrict__ stats) {
    int c = blockIdx.x;
    int tid = threadIdx.x;
    float s = 0.f, sq = 0.f;
    for (int b = 0; b < B; ++b) {
        const float* p = wy + ((size_t)b * C + c) * NN;
        #pragma unroll 4
        for (int k = 0; k < 16; ++k) {
            float v = p[tid + k * 256];
            s += v;
            sq = fmaf(v, v, sq);
        }
    }
    #pragma unroll
    for (int o = 32; o >= 1; o >>= 1) {
        s  += __shfl_down(s, o);
        sq += __shfl_down(sq, o);
    }
    __shared__ float rs[4], rq[4];
    int lane = tid & 63, wv = tid >> 6;
    if (lane == 0) { rs[wv] = s; rq[wv] = sq; }
    __syncthreads();
    if (tid == 0) {
        stats[c]       = rs[0] + rs[1] + rs[2] + rs[3];
        stats[256 + c] = rq[0] + rq[1] + rq[2] + rq[3];
    }
}

// ---------------------------------------------------------------- K5: BN apply + residual
__global__ __launch_bounds__(256) void k_bn_out(const float* __restrict__ wy,
        const float* __restrict__ x, const float* __restrict__ stats,
        const float* __restrict__ gamma, const float* __restrict__ beta,
        float* __restrict__ out) {
    size_t idx = (size_t)blockIdx.x * 256 + threadIdx.x;  // float4 index
    int c = (int)(((idx * 4) >> 12) & 255);
    float mean = stats[c] * (1.f / 32768.f);
    float var  = stats[256 + c] * (1.f / 32768.f) - mean * mean;
    float sc = gamma[c] * rsqrtf(var + EPS);
    float sh = beta[c] - mean * sc;
    float4 w4 = ((const float4*)wy)[idx];
    float4 x4 = ((const float4*)x)[idx];
    float4 o;
    o.x = fmaf(w4.x, sc, sh) + x4.x;
    o.y = fmaf(w4.y, sc, sh) + x4.y;
    o.z = fmaf(w4.z, sc, sh) + x4.z;
    o.w = fmaf(w4.w, sc, sh) + x4.w;
    ((float4*)out)[idx] = o;
}

// ----------------------------------------------------------------
extern "C" void kernel_launch(void* const* d_in, const int* in_sizes, int n_in,
                              void* d_out, int out_size, void* d_ws, size_t ws_size,
                              hipStream_t stream) {
    const float* x    = (const float*)d_in[0];
    const float* g_w  = (const float*)d_in[1];
    const float* g_b  = (const float*)d_in[2];
    const float* th_w = (const float*)d_in[3];
    const float* th_b = (const float*)d_in[4];
    const float* ph_w = (const float*)d_in[5];
    const float* ph_b = (const float*)d_in[6];
    const float* w_w  = (const float*)d_in[7];
    const float* w_b  = (const float*)d_in[8];
    const float* bn_g = (const float*)d_in[9];
    const float* bn_b = (const float*)d_in[10];
    float* out = (float*)d_out;

    char* w0 = (char*)d_ws;
    // wy (f32, 33.5 MB) overlaps xh+theta (both dead before k_wconv writes wy)
    float*          wy    = (float*)w0;                          // [B][C][N] f32   33,554,432 B
    unsigned short* xh    = (unsigned short*)w0;                 // [B][N][C] f16   16,777,216 B
    unsigned short* theta = (unsigned short*)(w0 + 16777216);    // [B][N][CI] f16   8,388,608 B
    unsigned short* wh    = (unsigned short*)(w0 + 33554432);    // 4x32768 f16        262,144 B
    unsigned short* twh   = wh;
    unsigned short* pwh   = wh + 32768;
    unsigned short* gwh   = wh + 65536;
    unsigned short* wwh   = wh + 98304;
    unsigned short* phi   = (unsigned short*)(w0 + 33816576);    // [B][m][CI] f16   2,097,152 B
    unsigned short* gx    = (unsigned short*)(w0 + 35913728);    // [B][CI][m] f16   2,097,152 B
    unsigned short* yh    = (unsigned short*)(w0 + 38010880);    // [B][N][CI] f16   8,388,608 B
    float*          stats = (float*)(w0 + 46399488);             // 512 f32

    k_prep<<<512, 256, 0, stream>>>(th_w, ph_w, g_w, w_w, wh);
    k_xt<<<dim3(64, 4, B), 256, 0, stream>>>(x, xh);
    k_conv_theta<<<512, 256, 0, stream>>>(xh, twh, th_b, theta);
    k_conv_pool<<<256, 512, 0, stream>>>(xh, pwh, ph_b, phi, 1);  // phi: [b][m][ci]
    k_conv_pool<<<256, 512, 0, stream>>>(xh, gwh, g_b, gx, 0);    // g:   [b][ci][m]
    k_attn_mfma<<<dim3(64, B), 256, 0, stream>>>(theta, phi, gx, yh);
    k_wconv<<<512, 256, 0, stream>>>(yh, wwh, w_b, wy);
    k_stats<<<256, 256, 0, stream>>>(wy, stats);
    k_bn_out<<<8192, 256, 0, stream>>>(wy, x, stats, bn_g, bn_b, out);
}

// Round 5
// 150.165 us; speedup vs baseline: 4.8453x; 1.5059x over previous
//
#include <hip/hip_runtime.h>
#include <hip/hip_bf16.h>
#include <hip/hip_fp16.h>
#include <math.h>

#define B 8
#define C 256
#define HH 64
#define WW 64
#define NN 4096      // H*W
#define CI 128
#define NS 1024      // pooled spatial
#define EPS 1e-5f

typedef __attribute__((ext_vector_type(8))) _Float16 f16x8;
typedef __attribute__((ext_vector_type(4))) float f32x4;

static __device__ __forceinline__ unsigned short f2h_bits(float f) {
    return __half_as_ushort(__float2half(f));   // v_cvt_f16_f32 (RNE)
}

// ---------------------------------------------------------------- K0: weights -> f16
__global__ __launch_bounds__(256) void k_prep(const float* __restrict__ tw,
        const float* __restrict__ pw, const float* __restrict__ gw,
        const float* __restrict__ ww, unsigned short* __restrict__ wh) {
    int idx = blockIdx.x * 256 + threadIdx.x;          // 0..131071
    int sel = idx >> 15, off = idx & 32767;
    const float* src = (sel == 0) ? tw : (sel == 1) ? pw : (sel == 2) ? gw : ww;
    wh[idx] = f2h_bits(src[off]);
}

// ---------------------------------------------------------------- K0b: x [b][c][n] f32 -> xh [b][n][c] f16
__global__ __launch_bounds__(256) void k_xt(const float* __restrict__ x,
                                            unsigned short* __restrict__ xh) {
    __shared__ float s_t[64 * 65];
    int n0 = blockIdx.x * 64;
    int c0 = blockIdx.y * 64;
    int b  = blockIdx.z;
    int tid = threadIdx.x;
    #pragma unroll
    for (int k = 0; k < 16; ++k) {
        int idx = tid + k * 256;           // 0..4095
        int cl = idx >> 6, nl = idx & 63;
        s_t[cl * 65 + nl] = x[((size_t)b * C + c0 + cl) * NN + n0 + nl];
    }
    __syncthreads();
    #pragma unroll
    for (int k = 0; k < 8; ++k) {
        int idx = tid + k * 256;           // 0..2047
        int nl = idx >> 5, cp = (idx & 31) * 2;
        ushort2 o;
        o.x = f2h_bits(s_t[cp * 65 + nl]);
        o.y = f2h_bits(s_t[(cp + 1) * 65 + nl]);
        *(ushort2*)&xh[((size_t)b * NN + n0 + nl) * C + c0 + cp] = o;
    }
}

// ---------------------------------------------------------------- K1: theta conv (MFMA)
__global__ __launch_bounds__(256) void k_conv_theta(const unsigned short* __restrict__ xh,
        const unsigned short* __restrict__ twh, const float* __restrict__ tb,
        unsigned short* __restrict__ theta) {
    int blk = blockIdx.x;                 // 512 blocks of 64 rows
    int tid = threadIdx.x;
    int lane = tid & 63, wv = tid >> 6;
    int lr = lane & 15, lh = lane >> 4;
    int rowf = blk * 64 + wv * 16 + lr;   // A-frag row

    f32x4 acc[8];
    #pragma unroll
    for (int i = 0; i < 8; ++i) acc[i] = (f32x4){0.f, 0.f, 0.f, 0.f};

    const unsigned short* ap = xh + (size_t)rowf * C + lh * 8;
    #pragma unroll
    for (int kc = 0; kc < 8; ++kc) {
        f16x8 a = *(const f16x8*)(ap + kc * 32);
        #pragma unroll
        for (int ct = 0; ct < 8; ++ct) {
            f16x8 bf = *(const f16x8*)&twh[(ct * 16 + lr) * C + kc * 32 + lh * 8];
            acc[ct] = __builtin_amdgcn_mfma_f32_16x16x32_f16(a, bf, acc[ct], 0, 0, 0);
        }
    }
    int rowo = blk * 64 + wv * 16 + lh * 4;
    #pragma unroll
    for (int ct = 0; ct < 8; ++ct) {
        int ci = ct * 16 + lr;
        float bias = tb[ci];
        #pragma unroll
        for (int r = 0; r < 4; ++r)
            theta[(size_t)(rowo + r) * CI + ci] = f2h_bits(acc[ct][r] + bias);
    }
}

// ---------------------------------------------------------------- K2: merged pooled conv (phi AND g, MFMA, in-reg 2x2 maxpool)
// block: 128 n-rows (= 2 h-rows), 512 thr / 8 waves; wave (wn=wv&3, wc=wv>>2)
// phi -> [b][m][ci]; g -> [b][ci][m]
__global__ __launch_bounds__(512) void k_conv_pool2(const unsigned short* __restrict__ xh,
        const unsigned short* __restrict__ pwh, const unsigned short* __restrict__ gwh,
        const float* __restrict__ pb, const float* __restrict__ gb_,
        unsigned short* __restrict__ phi, unsigned short* __restrict__ gout) {
    int blk = blockIdx.x;                 // 256 blocks
    int b   = blk >> 5;                   // 32 blocks per batch
    int mh  = blk & 31;                   // pooled h row
    int tid = threadIdx.x;
    int lane = tid & 63, wv = tid >> 6;
    int lr = lane & 15, lh = lane >> 4;
    int wn = wv & 3, wc = wv >> 2;
    size_t row0 = (size_t)blk * 128;

    f32x4 aP0[4], aP1[4], aG0[4], aG1[4];
    #pragma unroll
    for (int i = 0; i < 4; ++i) {
        aP0[i] = (f32x4){0,0,0,0}; aP1[i] = (f32x4){0,0,0,0};
        aG0[i] = (f32x4){0,0,0,0}; aG1[i] = (f32x4){0,0,0,0};
    }

    const unsigned short* ap0 = xh + (row0 + wn * 16 + lr) * C + lh * 8;
    const unsigned short* ap1 = ap0 + (size_t)64 * C;
    #pragma unroll
    for (int kc = 0; kc < 8; ++kc) {
        f16x8 a0 = *(const f16x8*)(ap0 + kc * 32);
        f16x8 a1 = *(const f16x8*)(ap1 + kc * 32);
        #pragma unroll
        for (int ct = 0; ct < 4; ++ct) {
            int wrow = (wc * 64 + ct * 16 + lr) * C + kc * 32 + lh * 8;
            f16x8 bp = *(const f16x8*)&pwh[wrow];
            f16x8 bg = *(const f16x8*)&gwh[wrow];
            aP0[ct] = __builtin_amdgcn_mfma_f32_16x16x32_f16(a0, bp, aP0[ct], 0, 0, 0);
            aP1[ct] = __builtin_amdgcn_mfma_f32_16x16x32_f16(a1, bp, aP1[ct], 0, 0, 0);
            aG0[ct] = __builtin_amdgcn_mfma_f32_16x16x32_f16(a0, bg, aG0[ct], 0, 0, 0);
            aG1[ct] = __builtin_amdgcn_mfma_f32_16x16x32_f16(a1, bg, aG1[ct], 0, 0, 0);
        }
    }
    // pool: w-adjacent = reg pairs (2j,2j+1); h-adjacent = acc0 vs acc1
    #pragma unroll
    for (int ct = 0; ct < 4; ++ct) {
        int ci = wc * 64 + ct * 16 + lr;
        float biasP = pb[ci], biasG = gb_[ci];
        #pragma unroll
        for (int j = 0; j < 2; ++j) {
            int m = mh * 32 + wn * 8 + lh * 2 + j;
            float vP = fmaxf(fmaxf(aP0[ct][2*j], aP0[ct][2*j+1]),
                             fmaxf(aP1[ct][2*j], aP1[ct][2*j+1])) + biasP;
            float vG = fmaxf(fmaxf(aG0[ct][2*j], aG0[ct][2*j+1]),
                             fmaxf(aG1[ct][2*j], aG1[ct][2*j+1])) + biasG;
            phi[((size_t)b * NS + m) * CI + ci]  = f2h_bits(vP);
            gout[((size_t)b * CI + ci) * NS + m] = f2h_bits(vG);
        }
    }
}

// ---------------------------------------------------------------- K3: fused attention (fp16 MFMA, LDS-staged tiles)
// theta [b][n][ci] f16, phi [b][m][ci] f16, g [b][ci][m] f16 -> y [b][n][ci] f16
#define SPH 136   // 128+8 f16 row stride
#define SG  72    // 64+8 f16
#define SP  72
__global__ __launch_bounds__(256) void k_attn_mfma(const unsigned short* __restrict__ theta,
        const unsigned short* __restrict__ phi, const unsigned short* __restrict__ g,
        unsigned short* __restrict__ y) {
    __shared__ unsigned short s_ph[64 * SPH];   // phi tile [m_local][ci]   17408 B
    __shared__ unsigned short s_g[128 * SG];    // g tile  [ci][m_local]    18432 B
    __shared__ unsigned short s_p[64 * SP];     // P       [row_local][m_local] 9216 B
    int rb = blockIdx.x;               // 64 row-blocks of 64
    int b  = blockIdx.y;
    int tid = threadIdx.x;
    int lane = tid & 63, wv = tid >> 6;
    int lr = lane & 15, lh = lane >> 4;
    int row0 = rb * 64;
    int wrow = wv * 16;

    f16x8 a_th[4];
    {
        const unsigned short* tp = theta + ((size_t)b * NN + row0 + wrow + lr) * CI + lh * 8;
        #pragma unroll
        for (int kc = 0; kc < 4; ++kc) a_th[kc] = *(const f16x8*)(tp + kc * 32);
    }

    f32x4 yacc[8];
    #pragma unroll
    for (int i = 0; i < 8; ++i) yacc[i] = (f32x4){0.f, 0.f, 0.f, 0.f};
    float mrun[4] = {-1e30f, -1e30f, -1e30f, -1e30f};
    float lrun[4] = {0.f, 0.f, 0.f, 0.f};

    for (int mt = 0; mt < 16; ++mt) {
        __syncthreads();   // protect s_ph/s_g from previous-iter readers
        {   // stage phi tile: 64 rows x 128 f16 (32 ushort4/row)
            const ushort4* src = (const ushort4*)(phi + ((size_t)b * NS + mt * 64) * CI);
            #pragma unroll
            for (int k = 0; k < 8; ++k) {
                int t = tid + k * 256;        // 0..2047
                int r = t >> 5, cq = t & 31;
                ushort4 vv = src[r * 32 + cq];
                *(ushort4*)&s_ph[r * SPH + cq * 4] = vv;
            }
            // stage g tile: 128 ci-rows x 64 m (16 ushort4/row)
            const ushort4* sg = (const ushort4*)(g + (size_t)b * CI * NS);
            #pragma unroll
            for (int k = 0; k < 8; ++k) {
                int t = tid + k * 256;
                int ci = t >> 4, cq = t & 15;
                ushort4 vv = sg[ci * 256 + mt * 16 + cq];
                *(ushort4*)&s_g[ci * SG + cq * 4] = vv;
            }
        }
        __syncthreads();

        // ---- S = theta * phi^T
        f32x4 S[4];
        #pragma unroll
        for (int nt = 0; nt < 4; ++nt) S[nt] = (f32x4){0.f, 0.f, 0.f, 0.f};
        #pragma unroll
        for (int nt = 0; nt < 4; ++nt) {
            #pragma unroll
            for (int kc = 0; kc < 4; ++kc) {
                f16x8 bf = *(const f16x8*)&s_ph[(nt * 16 + lr) * SPH + kc * 32 + lh * 8];
                S[nt] = __builtin_amdgcn_mfma_f32_16x16x32_f16(a_th[kc], bf, S[nt], 0, 0, 0);
            }
        }

        // ---- online softmax (rows lh*4+r; 16-lane col groups)
        float rmax[4], rs[4], scale[4];
        #pragma unroll
        for (int r = 0; r < 4; ++r)
            rmax[r] = fmaxf(fmaxf(S[0][r], S[1][r]), fmaxf(S[2][r], S[3][r]));
        #pragma unroll
        for (int s = 1; s < 16; s <<= 1) {
            #pragma unroll
            for (int r = 0; r < 4; ++r) rmax[r] = fmaxf(rmax[r], __shfl_xor(rmax[r], s));
        }
        #pragma unroll
        for (int r = 0; r < 4; ++r) {
            float mnew = fmaxf(mrun[r], rmax[r]);
            scale[r] = __expf(mrun[r] - mnew);
            mrun[r] = mnew;
            rs[r] = 0.f;
        }
        #pragma unroll
        for (int nt = 0; nt < 4; ++nt) {
            #pragma unroll
            for (int r = 0; r < 4; ++r) {
                float e = __expf(S[nt][r] - mrun[r]);
                S[nt][r] = e;
                rs[r] += e;
            }
        }
        #pragma unroll
        for (int s = 1; s < 16; s <<= 1) {
            #pragma unroll
            for (int r = 0; r < 4; ++r) rs[r] += __shfl_xor(rs[r], s);
        }
        #pragma unroll
        for (int r = 0; r < 4; ++r) lrun[r] = lrun[r] * scale[r] + rs[r];
        #pragma unroll
        for (int i = 0; i < 8; ++i) {
            #pragma unroll
            for (int r = 0; r < 4; ++r) yacc[i][r] *= scale[r];
        }
        // P -> wave-private LDS rows (same wave reads back; no barrier)
        #pragma unroll
        for (int nt = 0; nt < 4; ++nt) {
            #pragma unroll
            for (int r = 0; r < 4; ++r)
                s_p[(wrow + lh * 4 + r) * SP + nt * 16 + lr] = f2h_bits(S[nt][r]);
        }

        // ---- y += P * g
        f16x8 a_p[2];
        #pragma unroll
        for (int kc = 0; kc < 2; ++kc)
            a_p[kc] = *(const f16x8*)&s_p[(wrow + lr) * SP + kc * 32 + lh * 8];
        #pragma unroll
        for (int ct = 0; ct < 8; ++ct) {
            #pragma unroll
            for (int kc = 0; kc < 2; ++kc) {
                f16x8 bg = *(const f16x8*)&s_g[(ct * 16 + lr) * SG + kc * 32 + lh * 8];
                yacc[ct] = __builtin_amdgcn_mfma_f32_16x16x32_f16(a_p[kc], bg, yacc[ct], 0, 0, 0);
            }
        }
    }

    float inv[4];
    #pragma unroll
    for (int r = 0; r < 4; ++r) inv[r] = 1.f / lrun[r];
    #pragma unroll
    for (int ct = 0; ct < 8; ++ct) {
        #pragma unroll
        for (int r = 0; r < 4; ++r)
            y[((size_t)b * NN + row0 + wrow + lh * 4 + r) * CI + ct * 16 + lr] =
                f2h_bits(yacc[ct][r] * inv[r]);
    }
}

// ---------------------------------------------------------------- K4: W conv (MFMA)
__global__ __launch_bounds__(256) void k_wconv(const unsigned short* __restrict__ y,
        const unsigned short* __restrict__ wwh, const float* __restrict__ wb,
        float* __restrict__ wy) {
    int blk = blockIdx.x;                  // 512 blocks of 64 n
    int b   = blk >> 6;
    int nloc = (blk & 63) * 64;
    int tid = threadIdx.x;
    int lane = tid & 63, wv = tid >> 6;
    int lr = lane & 15, lh = lane >> 4;

    f32x4 acc[4][4];
    #pragma unroll
    for (int i = 0; i < 4; ++i)
        #pragma unroll
        for (int j = 0; j < 4; ++j) acc[i][j] = (f32x4){0.f, 0.f, 0.f, 0.f};

    const unsigned short* yb = y + ((size_t)b * NN + nloc) * CI;
    #pragma unroll
    for (int kc = 0; kc < 4; ++kc) {
        f16x8 a[4], bf[4];
        #pragma unroll
        for (int at = 0; at < 4; ++at)
            a[at] = *(const f16x8*)&wwh[(wv * 64 + at * 16 + lr) * CI + kc * 32 + lh * 8];
        #pragma unroll
        for (int bt = 0; bt < 4; ++bt)
            bf[bt] = *(const f16x8*)&yb[(size_t)(bt * 16 + lr) * CI + kc * 32 + lh * 8];
        #pragma unroll
        for (int at = 0; at < 4; ++at)
            #pragma unroll
            for (int bt = 0; bt < 4; ++bt)
                acc[at][bt] = __builtin_amdgcn_mfma_f32_16x16x32_f16(a[at], bf[bt], acc[at][bt], 0, 0, 0);
    }
    #pragma unroll
    for (int at = 0; at < 4; ++at) {
        #pragma unroll
        for (int r = 0; r < 4; ++r) {
            int co = wv * 64 + at * 16 + lh * 4 + r;
            float bias = wb[co];
            float* wp = wy + ((size_t)b * C + co) * NN + nloc;
            #pragma unroll
            for (int bt = 0; bt < 4; ++bt)
                wp[bt * 16 + lr] = acc[at][bt][r] + bias;
        }
    }
}

// ---------------------------------------------------------------- K4b: per-channel BN stats (deterministic)
__global__ __launch_bounds__(256) void k_stats(const float* __restrict__ wy,
                                               float* __restrict__ stats) {
    int c = blockIdx.x;
    int tid = threadIdx.x;
    float s = 0.f, sq = 0.f;
    for (int b = 0; b < B; ++b) {
        const float* p = wy + ((size_t)b * C + c) * NN;
        #pragma unroll 4
        for (int k = 0; k < 16; ++k) {
            float v = p[tid + k * 256];
            s += v;
            sq = fmaf(v, v, sq);
        }
    }
    #pragma unroll
    for (int o = 32; o >= 1; o >>= 1) {
        s  += __shfl_down(s, o);
        sq += __shfl_down(sq, o);
    }
    __shared__ float rs[4], rq[4];
    int lane = tid & 63, wv = tid >> 6;
    if (lane == 0) { rs[wv] = s; rq[wv] = sq; }
    __syncthreads();
    if (tid == 0) {
        stats[c]       = rs[0] + rs[1] + rs[2] + rs[3];
        stats[256 + c] = rq[0] + rq[1] + rq[2] + rq[3];
    }
}

// ---------------------------------------------------------------- K5: BN apply + residual
__global__ __launch_bounds__(256) void k_bn_out(const float* __restrict__ wy,
        const float* __restrict__ x, const float* __restrict__ stats,
        const float* __restrict__ gamma, const float* __restrict__ beta,
        float* __restrict__ out) {
    size_t idx = (size_t)blockIdx.x * 256 + threadIdx.x;  // float4 index
    int c = (int)(((idx * 4) >> 12) & 255);
    float mean = stats[c] * (1.f / 32768.f);
    float var  = stats[256 + c] * (1.f / 32768.f) - mean * mean;
    float sc = gamma[c] * rsqrtf(var + EPS);
    float sh = beta[c] - mean * sc;
    float4 w4 = ((const float4*)wy)[idx];
    float4 x4 = ((const float4*)x)[idx];
    float4 o;
    o.x = fmaf(w4.x, sc, sh) + x4.x;
    o.y = fmaf(w4.y, sc, sh) + x4.y;
    o.z = fmaf(w4.z, sc, sh) + x4.z;
    o.w = fmaf(w4.w, sc, sh) + x4.w;
    ((float4*)out)[idx] = o;
}

// ----------------------------------------------------------------
extern "C" void kernel_launch(void* const* d_in, const int* in_sizes, int n_in,
                              void* d_out, int out_size, void* d_ws, size_t ws_size,
                              hipStream_t stream) {
    const float* x    = (const float*)d_in[0];
    const float* g_w  = (const float*)d_in[1];
    const float* g_b  = (const float*)d_in[2];
    const float* th_w = (const float*)d_in[3];
    const float* th_b = (const float*)d_in[4];
    const float* ph_w = (const float*)d_in[5];
    const float* ph_b = (const float*)d_in[6];
    const float* w_w  = (const float*)d_in[7];
    const float* w_b  = (const float*)d_in[8];
    const float* bn_g = (const float*)d_in[9];
    const float* bn_b = (const float*)d_in[10];
    float* out = (float*)d_out;

    char* w0 = (char*)d_ws;
    // wy (f32, 33.5 MB) overlaps xh+theta (both dead before k_wconv writes wy)
    float*          wy    = (float*)w0;                          // [B][C][N] f32   33,554,432 B
    unsigned short* xh    = (unsigned short*)w0;                 // [B][N][C] f16   16,777,216 B
    unsigned short* theta = (unsigned short*)(w0 + 16777216);    // [B][N][CI] f16   8,388,608 B
    unsigned short* wh    = (unsigned short*)(w0 + 33554432);    // 4x32768 f16        262,144 B
    unsigned short* twh   = wh;
    unsigned short* pwh   = wh + 32768;
    unsigned short* gwh   = wh + 65536;
    unsigned short* wwh   = wh + 98304;
    unsigned short* phi   = (unsigned short*)(w0 + 33816576);    // [B][m][CI] f16   2,097,152 B
    unsigned short* gx    = (unsigned short*)(w0 + 35913728);    // [B][CI][m] f16   2,097,152 B
    unsigned short* yh    = (unsigned short*)(w0 + 38010880);    // [B][N][CI] f16   8,388,608 B
    float*          stats = (float*)(w0 + 46399488);             // 512 f32

    k_prep<<<512, 256, 0, stream>>>(th_w, ph_w, g_w, w_w, wh);
    k_xt<<<dim3(64, 4, B), 256, 0, stream>>>(x, xh);
    k_conv_theta<<<512, 256, 0, stream>>>(xh, twh, th_b, theta);
    k_conv_pool2<<<256, 512, 0, stream>>>(xh, pwh, gwh, ph_b, g_b, phi, gx);
    k_attn_mfma<<<dim3(64, B), 256, 0, stream>>>(theta, phi, gx, yh);
    k_wconv<<<512, 256, 0, stream>>>(yh, wwh, w_b, wy);
    k_stats<<<256, 256, 0, stream>>>(wy, stats);
    k_bn_out<<<8192, 256, 0, stream>>>(wy, x, stats, bn_g, bn_b, out);
}

// Round 6
// 131.777 us; speedup vs baseline: 5.5214x; 1.1395x over previous
//
#include <hip/hip_runtime.h>
#include <hip/hip_bf16.h>
#include <hip/hip_fp16.h>
#include <math.h>

#define B 8
#define C 256
#define HH 64
#define WW 64
#define NN 4096      // H*W
#define CI 128
#define NS 1024      // pooled spatial
#define EPS 1e-5f

typedef __attribute__((ext_vector_type(8))) _Float16 f16x8;
typedef __attribute__((ext_vector_type(4))) float f32x4;

static __device__ __forceinline__ unsigned short f2h_bits(float f) {
    return __half_as_ushort(__float2half(f));   // v_cvt_f16_f32 (RNE)
}
static __device__ __forceinline__ float h2f(unsigned short u) {
    return __half2float(__ushort_as_half(u));
}

// ---------------------------------------------------------------- K0: x transpose->f16 (+ weight prep folded in)
// x [b][c][n] f32 -> xh [b][n][c] f16;  blocks with nb==64 convert the 4 weight arrays
__global__ __launch_bounds__(256) void k_xt(const float* __restrict__ x,
        unsigned short* __restrict__ xh,
        const float* __restrict__ tw, const float* __restrict__ pw,
        const float* __restrict__ gw, const float* __restrict__ ww,
        unsigned short* __restrict__ wh) {
    int tid = threadIdx.x;
    if (blockIdx.x == 64) {   // weight prep: 32 instances x 4096 elements
        int inst = blockIdx.y * B + blockIdx.z;       // 0..31
        int base = inst * 4096;
        #pragma unroll
        for (int k = 0; k < 16; ++k) {
            int idx = base + tid + k * 256;           // 0..131071
            int sel = idx >> 15, off = idx & 32767;
            const float* src = (sel == 0) ? tw : (sel == 1) ? pw : (sel == 2) ? gw : ww;
            wh[idx] = f2h_bits(src[off]);
        }
        return;
    }
    __shared__ float s_t[64 * 65];
    int n0 = blockIdx.x * 64;
    int c0 = blockIdx.y * 64;
    int b  = blockIdx.z;
    #pragma unroll
    for (int k = 0; k < 16; ++k) {
        int idx = tid + k * 256;           // 0..4095
        int cl = idx >> 6, nl = idx & 63;
        s_t[cl * 65 + nl] = x[((size_t)b * C + c0 + cl) * NN + n0 + nl];
    }
    __syncthreads();
    #pragma unroll
    for (int k = 0; k < 8; ++k) {
        int idx = tid + k * 256;           // 0..2047
        int nl = idx >> 5, cp = (idx & 31) * 2;
        ushort2 o;
        o.x = f2h_bits(s_t[cp * 65 + nl]);
        o.y = f2h_bits(s_t[(cp + 1) * 65 + nl]);
        *(ushort2*)&xh[((size_t)b * NN + n0 + nl) * C + c0 + cp] = o;
    }
}

// ---------------------------------------------------------------- K1: fused theta + pooled phi/g convs (MFMA)
// block: 128 n-rows (=2 h-rows of pooling), 512 thr / 8 waves.
// wave wv: theta rows wv*16..+15; pool A-frags rows wn*16 and wn*16+64 (wn=wv&3),
//          pool ci range wc*64..+63 (wc=wv>>2). Note theta rows == one pool frag.
__global__ __launch_bounds__(512) void k_convs(const unsigned short* __restrict__ xh,
        const unsigned short* __restrict__ twh, const unsigned short* __restrict__ pwh,
        const unsigned short* __restrict__ gwh,
        const float* __restrict__ tb, const float* __restrict__ pb, const float* __restrict__ gb_,
        unsigned short* __restrict__ theta, unsigned short* __restrict__ phi,
        unsigned short* __restrict__ gout) {
    int blk = blockIdx.x;                 // 256 blocks
    int b   = blk >> 5;
    int mh  = blk & 31;                   // pooled h row
    int tid = threadIdx.x;
    int lane = tid & 63, wv = tid >> 6;
    int lr = lane & 15, lh = lane >> 4;
    int wn = wv & 3, wc = wv >> 2;
    size_t row0 = (size_t)blk * 128;

    f32x4 accT[8];
    f32x4 aP0[4], aP1[4], aG0[4], aG1[4];
    #pragma unroll
    for (int i = 0; i < 8; ++i) accT[i] = (f32x4){0,0,0,0};
    #pragma unroll
    for (int i = 0; i < 4; ++i) {
        aP0[i] = (f32x4){0,0,0,0}; aP1[i] = (f32x4){0,0,0,0};
        aG0[i] = (f32x4){0,0,0,0}; aG1[i] = (f32x4){0,0,0,0};
    }

    const unsigned short* ap0 = xh + (row0 + wn * 16 + lr) * C + lh * 8;
    const unsigned short* ap1 = ap0 + (size_t)64 * C;
    #pragma unroll
    for (int kc = 0; kc < 8; ++kc) {
        f16x8 a0 = *(const f16x8*)(ap0 + kc * 32);
        f16x8 a1 = *(const f16x8*)(ap1 + kc * 32);
        f16x8 aT = (wv < 4) ? a0 : a1;
        #pragma unroll
        for (int ct = 0; ct < 8; ++ct) {
            f16x8 bt_ = *(const f16x8*)&twh[(ct * 16 + lr) * C + kc * 32 + lh * 8];
            accT[ct] = __builtin_amdgcn_mfma_f32_16x16x32_f16(aT, bt_, accT[ct], 0, 0, 0);
        }
        #pragma unroll
        for (int ct = 0; ct < 4; ++ct) {
            int wrow = (wc * 64 + ct * 16 + lr) * C + kc * 32 + lh * 8;
            f16x8 bp = *(const f16x8*)&pwh[wrow];
            f16x8 bg = *(const f16x8*)&gwh[wrow];
            aP0[ct] = __builtin_amdgcn_mfma_f32_16x16x32_f16(a0, bp, aP0[ct], 0, 0, 0);
            aP1[ct] = __builtin_amdgcn_mfma_f32_16x16x32_f16(a1, bp, aP1[ct], 0, 0, 0);
            aG0[ct] = __builtin_amdgcn_mfma_f32_16x16x32_f16(a0, bg, aG0[ct], 0, 0, 0);
            aG1[ct] = __builtin_amdgcn_mfma_f32_16x16x32_f16(a1, bg, aG1[ct], 0, 0, 0);
        }
    }
    // theta write: D-layout rows lh*4+r
    #pragma unroll
    for (int ct = 0; ct < 8; ++ct) {
        int ci = ct * 16 + lr;
        float bias = tb[ci];
        #pragma unroll
        for (int r = 0; r < 4; ++r)
            theta[(row0 + wv * 16 + lh * 4 + r) * CI + ci] = f2h_bits(accT[ct][r] + bias);
    }
    // 2x2 maxpool: w-adjacent = reg pairs (2j,2j+1); h-adjacent = acc0 vs acc1
    #pragma unroll
    for (int ct = 0; ct < 4; ++ct) {
        int ci = wc * 64 + ct * 16 + lr;
        float biasP = pb[ci], biasG = gb_[ci];
        #pragma unroll
        for (int j = 0; j < 2; ++j) {
            int m = mh * 32 + wn * 8 + lh * 2 + j;
            float vP = fmaxf(fmaxf(aP0[ct][2*j], aP0[ct][2*j+1]),
                             fmaxf(aP1[ct][2*j], aP1[ct][2*j+1])) + biasP;
            float vG = fmaxf(fmaxf(aG0[ct][2*j], aG0[ct][2*j+1]),
                             fmaxf(aG1[ct][2*j], aG1[ct][2*j+1])) + biasG;
            phi[((size_t)b * NS + m) * CI + ci]  = f2h_bits(vP);
            gout[((size_t)b * CI + ci) * NS + m] = f2h_bits(vG);
        }
    }
}

// ---------------------------------------------------------------- K3: fused attention (fp16 MFMA, dbuf, 1 barrier/tile)
#define SPH 136   // 128+8 f16 row stride
#define SG  72    // 64+8 f16
#define SP  68    // 64+4 f16 (2-way read alias = free; conflict-free writes)
__global__ __launch_bounds__(256) void k_attn_mfma(const unsigned short* __restrict__ theta,
        const unsigned short* __restrict__ phi, const unsigned short* __restrict__ g,
        unsigned short* __restrict__ y) {
    __shared__ unsigned short s_ph[2][64 * SPH];   // 2 x 17408 B
    __shared__ unsigned short s_g[2][128 * SG];    // 2 x 18432 B
    __shared__ unsigned short s_p[64 * SP];        // 8704 B  (total 80384 B -> 2 blocks/CU)
    int rb = blockIdx.x;               // 64 row-blocks of 64
    int b  = blockIdx.y;
    int tid = threadIdx.x;
    int lane = tid & 63, wv = tid >> 6;
    int lr = lane & 15, lh = lane >> 4;
    int row0 = rb * 64;
    int wrow = wv * 16;

    // theta A-fragments, loaded once
    f16x8 a_th[4];
    {
        const unsigned short* tp = theta + ((size_t)b * NN + row0 + wrow + lr) * CI + lh * 8;
        #pragma unroll
        for (int kc = 0; kc < 4; ++kc) a_th[kc] = *(const f16x8*)(tp + kc * 32);
    }

    const ushort4* phsrc = (const ushort4*)(phi + (size_t)b * NS * CI);
    const ushort4* gsrc  = (const ushort4*)(g + (size_t)b * CI * NS);

    f32x4 yacc[8];
    #pragma unroll
    for (int i = 0; i < 8; ++i) yacc[i] = (f32x4){0.f, 0.f, 0.f, 0.f};
    float mrun[4] = {-1e30f, -1e30f, -1e30f, -1e30f};
    float lrun[4] = {0.f, 0.f, 0.f, 0.f};

    ushort4 rph[8], rg[8];
    // prologue: stage tile 0
    #pragma unroll
    for (int k = 0; k < 8; ++k) {
        int t = tid + k * 256;
        rph[k] = phsrc[(t >> 5) * 32 + (t & 31)];           // tile 0: rows 0..63
        rg[k]  = gsrc[(t >> 4) * 256 + (t & 15)];           // tile 0: cols 0..63
    }
    #pragma unroll
    for (int k = 0; k < 8; ++k) {
        int t = tid + k * 256;
        *(ushort4*)&s_ph[0][(t >> 5) * SPH + (t & 31) * 4] = rph[k];
        *(ushort4*)&s_g[0][(t >> 4) * SG + (t & 15) * 4]   = rg[k];
    }
    __syncthreads();
    int cur = 0;

    for (int mt = 0; mt < 16; ++mt) {
        // issue next tile's global loads (latency hides under compute)
        if (mt < 15) {
            #pragma unroll
            for (int k = 0; k < 8; ++k) {
                int t = tid + k * 256;
                rph[k] = phsrc[((mt + 1) * 64 + (t >> 5)) * 32 + (t & 31)];
                rg[k]  = gsrc[(t >> 4) * 256 + (mt + 1) * 16 + (t & 15)];
            }
        }
        const unsigned short* ph = s_ph[cur];
        const unsigned short* sg_ = s_g[cur];

        // ---- S = theta * phi^T
        f32x4 S[4];
        #pragma unroll
        for (int nt = 0; nt < 4; ++nt) S[nt] = (f32x4){0.f, 0.f, 0.f, 0.f};
        __builtin_amdgcn_s_setprio(1);
        #pragma unroll
        for (int nt = 0; nt < 4; ++nt) {
            #pragma unroll
            for (int kc = 0; kc < 4; ++kc) {
                f16x8 bf = *(const f16x8*)&ph[(nt * 16 + lr) * SPH + kc * 32 + lh * 8];
                S[nt] = __builtin_amdgcn_mfma_f32_16x16x32_f16(a_th[kc], bf, S[nt], 0, 0, 0);
            }
        }
        __builtin_amdgcn_s_setprio(0);

        // ---- online softmax (rows lh*4+r; 16-lane col groups)
        float rmax[4], rs[4], scale[4];
        #pragma unroll
        for (int r = 0; r < 4; ++r)
            rmax[r] = fmaxf(fmaxf(S[0][r], S[1][r]), fmaxf(S[2][r], S[3][r]));
        #pragma unroll
        for (int s = 1; s < 16; s <<= 1) {
            #pragma unroll
            for (int r = 0; r < 4; ++r) rmax[r] = fmaxf(rmax[r], __shfl_xor(rmax[r], s));
        }
        #pragma unroll
        for (int r = 0; r < 4; ++r) {
            float mnew = fmaxf(mrun[r], rmax[r]);
            scale[r] = __expf(mrun[r] - mnew);
            mrun[r] = mnew;
            rs[r] = 0.f;
        }
        #pragma unroll
        for (int nt = 0; nt < 4; ++nt) {
            #pragma unroll
            for (int r = 0; r < 4; ++r) {
                float e = __expf(S[nt][r] - mrun[r]);
                S[nt][r] = e;
                rs[r] += e;
            }
        }
        #pragma unroll
        for (int s = 1; s < 16; s <<= 1) {
            #pragma unroll
            for (int r = 0; r < 4; ++r) rs[r] += __shfl_xor(rs[r], s);
        }
        #pragma unroll
        for (int r = 0; r < 4; ++r) lrun[r] = lrun[r] * scale[r] + rs[r];
        #pragma unroll
        for (int i = 0; i < 8; ++i) {
            #pragma unroll
            for (int r = 0; r < 4; ++r) yacc[i][r] *= scale[r];
        }
        // P -> wave-private LDS rows (same wave reads back; no barrier)
        #pragma unroll
        for (int nt = 0; nt < 4; ++nt) {
            #pragma unroll
            for (int r = 0; r < 4; ++r)
                s_p[(wrow + lh * 4 + r) * SP + nt * 16 + lr] = f2h_bits(S[nt][r]);
        }

        // ---- y += P * g
        f16x8 a_p[2];
        #pragma unroll
        for (int kc = 0; kc < 2; ++kc)
            a_p[kc] = *(const f16x8*)&s_p[(wrow + lr) * SP + kc * 32 + lh * 8];
        __builtin_amdgcn_s_setprio(1);
        #pragma unroll
        for (int ct = 0; ct < 8; ++ct) {
            #pragma unroll
            for (int kc = 0; kc < 2; ++kc) {
                f16x8 bg = *(const f16x8*)&sg_[(ct * 16 + lr) * SG + kc * 32 + lh * 8];
                yacc[ct] = __builtin_amdgcn_mfma_f32_16x16x32_f16(a_p[kc], bg, yacc[ct], 0, 0, 0);
            }
        }
        __builtin_amdgcn_s_setprio(0);

        // ---- write staged regs into the other buffer; single barrier
        if (mt < 15) {
            int nxt = cur ^ 1;
            #pragma unroll
            for (int k = 0; k < 8; ++k) {
                int t = tid + k * 256;
                *(ushort4*)&s_ph[nxt][(t >> 5) * SPH + (t & 31) * 4] = rph[k];
                *(ushort4*)&s_g[nxt][(t >> 4) * SG + (t & 15) * 4]   = rg[k];
            }
            __syncthreads();
            cur = nxt;
        }
    }

    float inv[4];
    #pragma unroll
    for (int r = 0; r < 4; ++r) inv[r] = 1.f / lrun[r];
    #pragma unroll
    for (int ct = 0; ct < 8; ++ct) {
        #pragma unroll
        for (int r = 0; r < 4; ++r)
            y[((size_t)b * NN + row0 + wrow + lh * 4 + r) * CI + ct * 16 + lr] =
                f2h_bits(yacc[ct][r] * inv[r]);
    }
}

// ---------------------------------------------------------------- K4: W conv (MFMA) -> f16 wy + BN partial sums
__global__ __launch_bounds__(256) void k_wconv(const unsigned short* __restrict__ y,
        const unsigned short* __restrict__ wwh, const float* __restrict__ wb,
        unsigned short* __restrict__ wyh, float* __restrict__ psum, float* __restrict__ psq) {
    int blk = blockIdx.x;                  // 512 blocks of 64 n
    int b   = blk >> 6;
    int nloc = (blk & 63) * 64;
    int tid = threadIdx.x;
    int lane = tid & 63, wv = tid >> 6;
    int lr = lane & 15, lh = lane >> 4;

    f32x4 acc[4][4];
    #pragma unroll
    for (int i = 0; i < 4; ++i)
        #pragma unroll
        for (int j = 0; j < 4; ++j) acc[i][j] = (f32x4){0.f, 0.f, 0.f, 0.f};

    const unsigned short* yb = y + ((size_t)b * NN + nloc) * CI;
    #pragma unroll
    for (int kc = 0; kc < 4; ++kc) {
        f16x8 a[4], bf[4];
        #pragma unroll
        for (int at = 0; at < 4; ++at)
            a[at] = *(const f16x8*)&wwh[(wv * 64 + at * 16 + lr) * CI + kc * 32 + lh * 8];
        #pragma unroll
        for (int bt = 0; bt < 4; ++bt)
            bf[bt] = *(const f16x8*)&yb[(size_t)(bt * 16 + lr) * CI + kc * 32 + lh * 8];
        #pragma unroll
        for (int at = 0; at < 4; ++at)
            #pragma unroll
            for (int bt = 0; bt < 4; ++bt)
                acc[at][bt] = __builtin_amdgcn_mfma_f32_16x16x32_f16(a[at], bf[bt], acc[at][bt], 0, 0, 0);
    }
    #pragma unroll
    for (int at = 0; at < 4; ++at) {
        #pragma unroll
        for (int r = 0; r < 4; ++r) {
            int co = wv * 64 + at * 16 + lh * 4 + r;
            float bias = wb[co];
            unsigned short* wp = wyh + ((size_t)b * C + co) * NN + nloc;
            float s = 0.f, q = 0.f;
            #pragma unroll
            for (int bt = 0; bt < 4; ++bt) {
                float v = acc[at][bt][r] + bias;
                wp[bt * 16 + lr] = f2h_bits(v);
                s += v;
                q = fmaf(v, v, q);
            }
            // reduce over the 16 lr lanes (lane bits 0-3)
            #pragma unroll
            for (int o = 1; o < 16; o <<= 1) {
                s += __shfl_xor(s, o);
                q += __shfl_xor(q, o);
            }
            if (lr == 0) {
                psum[co * 512 + blk] = s;
                psq[co * 512 + blk]  = q;
            }
        }
    }
}

// ---------------------------------------------------------------- K4b: reduce BN partials
__global__ __launch_bounds__(64) void k_stats_r(const float* __restrict__ psum,
        const float* __restrict__ psq, float* __restrict__ stats) {
    int c = blockIdx.x;
    int lane = threadIdx.x;
    float s = 0.f, q = 0.f;
    #pragma unroll
    for (int k = 0; k < 8; ++k) {
        s += psum[c * 512 + lane + k * 64];
        q += psq[c * 512 + lane + k * 64];
    }
    #pragma unroll
    for (int o = 32; o >= 1; o >>= 1) {
        s += __shfl_down(s, o);
        q += __shfl_down(q, o);
    }
    if (lane == 0) { stats[c] = s; stats[256 + c] = q; }
}

// ---------------------------------------------------------------- K5: BN apply + residual (f16 wy input)
__global__ __launch_bounds__(256) void k_bn_out(const unsigned short* __restrict__ wyh,
        const float* __restrict__ x, const float* __restrict__ stats,
        const float* __restrict__ gamma, const float* __restrict__ beta,
        float* __restrict__ out) {
    size_t t = (size_t)blockIdx.x * 256 + threadIdx.x;   // 8-element groups
    size_t base = t * 8;
    int c = (int)((base >> 12) & 255);
    float mean = stats[c] * (1.f / 32768.f);
    float var  = stats[256 + c] * (1.f / 32768.f) - mean * mean;
    float sc = gamma[c] * rsqrtf(var + EPS);
    float sh = beta[c] - mean * sc;
    ushort4 w0 = *(const ushort4*)&wyh[base];
    ushort4 w1 = *(const ushort4*)&wyh[base + 4];
    float4 x0 = *(const float4*)&x[base];
    float4 x1 = *(const float4*)&x[base + 4];
    float4 o0, o1;
    o0.x = fmaf(h2f(w0.x), sc, sh) + x0.x;
    o0.y = fmaf(h2f(w0.y), sc, sh) + x0.y;
    o0.z = fmaf(h2f(w0.z), sc, sh) + x0.z;
    o0.w = fmaf(h2f(w0.w), sc, sh) + x0.w;
    o1.x = fmaf(h2f(w1.x), sc, sh) + x1.x;
    o1.y = fmaf(h2f(w1.y), sc, sh) + x1.y;
    o1.z = fmaf(h2f(w1.z), sc, sh) + x1.z;
    o1.w = fmaf(h2f(w1.w), sc, sh) + x1.w;
    *(float4*)&out[base]     = o0;
    *(float4*)&out[base + 4] = o1;
}

// ----------------------------------------------------------------
extern "C" void kernel_launch(void* const* d_in, const int* in_sizes, int n_in,
                              void* d_out, int out_size, void* d_ws, size_t ws_size,
                              hipStream_t stream) {
    const float* x    = (const float*)d_in[0];
    const float* g_w  = (const float*)d_in[1];
    const float* g_b  = (const float*)d_in[2];
    const float* th_w = (const float*)d_in[3];
    const float* th_b = (const float*)d_in[4];
    const float* ph_w = (const float*)d_in[5];
    const float* ph_b = (const float*)d_in[6];
    const float* w_w  = (const float*)d_in[7];
    const float* w_b  = (const float*)d_in[8];
    const float* bn_g = (const float*)d_in[9];
    const float* bn_b = (const float*)d_in[10];
    float* out = (float*)d_out;

    char* w0 = (char*)d_ws;
    unsigned short* xh    = (unsigned short*)w0;                 // [B][N][C] f16   16,777,216 B
    unsigned short* theta = (unsigned short*)(w0 + 16777216);    // [B][N][CI] f16   8,388,608 B
    unsigned short* wh    = (unsigned short*)(w0 + 25165824);    // 4x32768 f16        262,144 B
    unsigned short* twh   = wh;
    unsigned short* pwh   = wh + 32768;
    unsigned short* gwh   = wh + 65536;
    unsigned short* wwh   = wh + 98304;
    unsigned short* phi   = (unsigned short*)(w0 + 25427968);    // [B][m][CI] f16   2,097,152 B
    unsigned short* gx    = (unsigned short*)(w0 + 27525120);    // [B][CI][m] f16   2,097,152 B
    unsigned short* yh    = (unsigned short*)(w0 + 29622272);    // [B][N][CI] f16   8,388,608 B
    unsigned short* wyh   = (unsigned short*)(w0 + 38010880);    // [B][C][N]  f16  16,777,216 B
    float*          psum  = (float*)(w0 + 54788096);             // [256][512] f32     524,288 B
    float*          psq   = (float*)(w0 + 55312384);             // [256][512] f32     524,288 B
    float*          stats = (float*)(w0 + 55836672);             // 512 f32

    k_xt<<<dim3(65, 4, B), 256, 0, stream>>>(x, xh, th_w, ph_w, g_w, w_w, wh);
    k_convs<<<256, 512, 0, stream>>>(xh, twh, pwh, gwh, th_b, ph_b, g_b, theta, phi, gx);
    k_attn_mfma<<<dim3(64, B), 256, 0, stream>>>(theta, phi, gx, yh);
    k_wconv<<<512, 256, 0, stream>>>(yh, wwh, w_b, wyh, psum, psq);
    k_stats_r<<<256, 64, 0, stream>>>(psum, psq, stats);
    k_bn_out<<<4096, 256, 0, stream>>>(wyh, x, stats, bn_g, bn_b, out);
}